// Round 3
// baseline (2493.667 us; speedup 1.0000x reference)
//
#include <hip/hip_runtime.h>
#include <hip/hip_bf16.h>

#define N_   128
#define L_   512
#define NB_  4
#define D_   1024
#define H_   16
#define DH_  64
#define IN_  1024
#define T_   512

#define KS_  8       // GEMM K-splits (Kc = 128)
#define NCV_ 8       // attention chunks per sample (64 rows each)

// ---------------------------------------------------------------- pos table
__global__ __launch_bounds__(512) void pos_kernel(float* __restrict__ pos) {
  int t = blockIdx.x;          // 0..511
  int j = threadIdx.x;         // 0..511
  float seq = (float)(T_ - 1 - t);
  float ex  = (float)(2 * j) * (1.0f / (float)D_);
  float inv = expf(-ex * 9.210340371976184f);   // 10000^(-2j/D)
  float si  = seq * inv;
  pos[(size_t)t * D_ + j]        = sinf(si);
  pos[(size_t)t * D_ + 512 + j]  = cosf(si);
}

// ---------------------------------------------------------------- LayerNorm (row of 1024)
__global__ __launch_bounds__(256) void ln_kernel(const float* __restrict__ in,
                                                 const float* __restrict__ g,
                                                 const float* __restrict__ b,
                                                 float* __restrict__ out) {
  int n = blockIdx.x, tid = threadIdx.x;
  float4 x = *(const float4*)&in[(size_t)n * D_ + tid * 4];
  float s = x.x + x.y + x.z + x.w;
  float q = x.x * x.x + x.y * x.y + x.z * x.z + x.w * x.w;
  __shared__ float sa[4], sb[4];
  #pragma unroll
  for (int o = 32; o; o >>= 1) { s += __shfl_xor(s, o, 64); q += __shfl_xor(q, o, 64); }
  if ((tid & 63) == 0) { sa[tid >> 6] = s; sb[tid >> 6] = q; }
  __syncthreads();
  s = sa[0] + sa[1] + sa[2] + sa[3];
  q = sb[0] + sb[1] + sb[2] + sb[3];
  float mean = s * (1.f / D_);
  float var  = q * (1.f / D_) - mean * mean;
  float rstd = rsqrtf(var + 1e-5f);
  float4 gg = *(const float4*)&g[tid * 4];
  float4 bb = *(const float4*)&b[tid * 4];
  float4 y;
  y.x = (x.x - mean) * rstd * gg.x + bb.x;
  y.y = (x.y - mean) * rstd * gg.y + bb.y;
  y.z = (x.z - mean) * rstd * gg.z + bb.z;
  y.w = (x.w - mean) * rstd * gg.w + bb.w;
  *(float4*)&out[(size_t)n * D_ + tid * 4] = y;
}

// ---------------------------------------------------------------- qk = scale * Wk[h] @ (q_ln[h] @ Wq[h])
__global__ __launch_bounds__(256) void qk_prep(const float* __restrict__ qln,
                                               const float* __restrict__ Wq,
                                               const float* __restrict__ Wk,
                                               float* __restrict__ qk) {
  int n = blockIdx.x, tid = threadIdx.x;
  __shared__ float qrow[D_];
  __shared__ float Qp[D_];
  *(float4*)&qrow[tid * 4] = *(const float4*)&qln[(size_t)n * D_ + tid * 4];
  __syncthreads();
  #pragma unroll
  for (int j = 0; j < 4; ++j) {
    int idx = tid + j * 256; int h = idx >> 6, e = idx & 63;
    float acc = 0.f;
    for (int d = 0; d < DH_; ++d)
      acc += qrow[(h << 6) + d] * Wq[((size_t)(h << 6) + d) * DH_ + e];
    Qp[idx] = acc;
  }
  __syncthreads();
  #pragma unroll
  for (int j = 0; j < 4; ++j) {
    int idx = tid + j * 256; int h = idx >> 6, d = idx & 63;
    float acc = 0.f;
    for (int e = 0; e < DH_; ++e)
      acc += Wk[((size_t)(h << 6) + d) * DH_ + e] * Qp[(h << 6) + e];
    qk[(size_t)n * D_ + idx] = acc * 0.03125f;   // 1/sqrt(1024)
  }
}

// ---------------------------------------------------------------- shared row loader: y = LN(mem+pos)
__device__ __forceinline__ void load_ln_row(const float* __restrict__ xr,
                                            const float* __restrict__ pr,
                                            const float* g, const float* bv,
                                            float* y) {
  float xv[16];
  #pragma unroll
  for (int j = 0; j < 4; ++j) {
    float4 a = *(const float4*)&xr[4 * j];
    float4 p = *(const float4*)&pr[4 * j];
    xv[4*j+0] = a.x + p.x; xv[4*j+1] = a.y + p.y;
    xv[4*j+2] = a.z + p.z; xv[4*j+3] = a.w + p.w;
  }
  float s1 = 0.f, s2 = 0.f;
  #pragma unroll
  for (int j = 0; j < 16; ++j) { s1 += xv[j]; s2 += xv[j] * xv[j]; }
  #pragma unroll
  for (int o = 32; o; o >>= 1) { s1 += __shfl_xor(s1, o, 64); s2 += __shfl_xor(s2, o, 64); }
  float mean = s1 * (1.f / D_);
  float var  = s2 * (1.f / D_) - mean * mean;
  float rstd = rsqrtf(var + 1e-5f);
  #pragma unroll
  for (int j = 0; j < 16; ++j) y[j] = (xv[j] - mean) * rstd * g[j] + bv[j];
}

// ---------------------------------------------------------------- pass A: energies E[n,h,l]
__global__ __launch_bounds__(256) void attn_energy(
    const float* __restrict__ mem, const float* __restrict__ pos,
    const int* __restrict__ mask, const int* __restrict__ midx,
    const float* __restrict__ qkv, const float* __restrict__ lng,
    const float* __restrict__ lnb, int blk, float* __restrict__ E)
{
  const int n    = blockIdx.y;
  const int w    = threadIdx.x >> 6;
  const int lane = threadIdx.x & 63;
  const int c    = blockIdx.x * 4 + w;      // 0..7
  const int l0   = c * (L_ / NCV_);         // 64 rows per wave
  const int d0   = lane * 16;

  float g[16], bv[16], qv[16];
  #pragma unroll
  for (int j = 0; j < 4; ++j) {
    float4 t0 = *(const float4*)&lng[d0 + 4 * j];
    g[4*j+0] = t0.x; g[4*j+1] = t0.y; g[4*j+2] = t0.z; g[4*j+3] = t0.w;
    float4 t1 = *(const float4*)&lnb[d0 + 4 * j];
    bv[4*j+0] = t1.x; bv[4*j+1] = t1.y; bv[4*j+2] = t1.z; bv[4*j+3] = t1.w;
    float4 t2 = *(const float4*)&qkv[(size_t)n * D_ + d0 + 4 * j];
    qv[4*j+0] = t2.x; qv[4*j+1] = t2.y; qv[4*j+2] = t2.z; qv[4*j+3] = t2.w;
  }
  for (int l = l0; l < l0 + (L_ / NCV_); ++l) {
    if (mask[(size_t)n * L_ + l] == 0) {
      if ((lane & 3) == 0)
        E[((size_t)n * H_ + (lane >> 2)) * L_ + l] = -3.125e18f;  // -1e20 * scale
      continue;
    }
    const float* xr = &mem[(((size_t)n * L_ + l) * NB_ + blk) * D_ + d0];
    const int tt = midx[(size_t)n * L_ + l];
    const float* pr = &pos[(size_t)tt * D_ + d0];
    float y[16];
    load_ln_row(xr, pr, g, bv, y);
    float e = 0.f;
    #pragma unroll
    for (int j = 0; j < 16; ++j) e += y[j] * qv[j];
    e += __shfl_xor(e, 1, 64);
    e += __shfl_xor(e, 2, 64);
    if ((lane & 3) == 0)
      E[((size_t)n * H_ + (lane >> 2)) * L_ + l] = e;
  }
}

// ---------------------------------------------------------------- exact softmax over L, in place
__global__ __launch_bounds__(256) void attn_soft(float* __restrict__ E) {
  int b = blockIdx.x, t = threadIdx.x;     // b = n*H + h
  size_t base = (size_t)b * L_;
  float e0 = E[base + t], e1 = E[base + 256 + t];
  float m = fmaxf(e0, e1);
  #pragma unroll
  for (int o = 32; o; o >>= 1) m = fmaxf(m, __shfl_xor(m, o, 64));
  __shared__ float redm[4];
  if ((t & 63) == 0) redm[t >> 6] = m;
  __syncthreads();
  m = fmaxf(fmaxf(redm[0], redm[1]), fmaxf(redm[2], redm[3]));
  float p0 = expf(e0 - m), p1 = expf(e1 - m);
  float s = p0 + p1;
  #pragma unroll
  for (int o = 32; o; o >>= 1) s += __shfl_xor(s, o, 64);
  __shared__ float reds[4];
  if ((t & 63) == 0) reds[t >> 6] = s;
  __syncthreads();
  s = reds[0] + reds[1] + reds[2] + reds[3];
  float inv = 1.f / s;
  E[base + t]       = p0 * inv;
  E[base + 256 + t] = p1 * inv;
}

// ---------------------------------------------------------------- pass B: av[n,d] partial = sum att*y
__global__ __launch_bounds__(256) void attn_apply(
    const float* __restrict__ mem, const float* __restrict__ pos,
    const int* __restrict__ midx, const float* __restrict__ att,
    const float* __restrict__ lng, const float* __restrict__ lnb,
    int blk, float* __restrict__ pav)
{
  const int n    = blockIdx.y;
  const int w    = threadIdx.x >> 6;
  const int lane = threadIdx.x & 63;
  const int c    = blockIdx.x * 4 + w;
  const int l0   = c * (L_ / NCV_);
  const int d0   = lane * 16;

  float g[16], bv[16];
  #pragma unroll
  for (int j = 0; j < 4; ++j) {
    float4 t0 = *(const float4*)&lng[d0 + 4 * j];
    g[4*j+0] = t0.x; g[4*j+1] = t0.y; g[4*j+2] = t0.z; g[4*j+3] = t0.w;
    float4 t1 = *(const float4*)&lnb[d0 + 4 * j];
    bv[4*j+0] = t1.x; bv[4*j+1] = t1.y; bv[4*j+2] = t1.z; bv[4*j+3] = t1.w;
  }
  float av[16];
  #pragma unroll
  for (int j = 0; j < 16; ++j) av[j] = 0.f;

  for (int l = l0; l < l0 + (L_ / NCV_); ++l) {
    float wgt = att[((size_t)n * H_ + (lane >> 2)) * L_ + l];  // 0 for masked rows
    const float* xr = &mem[(((size_t)n * L_ + l) * NB_ + blk) * D_ + d0];
    const int tt = midx[(size_t)n * L_ + l];
    const float* pr = &pos[(size_t)tt * D_ + d0];
    float y[16];
    load_ln_row(xr, pr, g, bv, y);
    #pragma unroll
    for (int j = 0; j < 16; ++j) av[j] += wgt * y[j];
  }
  size_t base = ((size_t)n * NCV_ + c) * D_ + d0;
  #pragma unroll
  for (int j = 0; j < 16; ++j) pav[base + j] = av[j];
}

// ---------------------------------------------------------------- sum chunks + V-projection -> tb
__global__ __launch_bounds__(256) void attn_fin2(const float* __restrict__ pav,
                                                 const float* __restrict__ Wv,
                                                 float* __restrict__ tb) {
  int n = blockIdx.x, tid = threadIdx.x;
  int d0 = tid * 4;
  float a0 = 0.f, a1 = 0.f, a2 = 0.f, a3 = 0.f;
  for (int c = 0; c < NCV_; ++c) {
    float4 v = *(const float4*)&pav[((size_t)n * NCV_ + c) * D_ + d0];
    a0 += v.x; a1 += v.y; a2 += v.z; a3 += v.w;
  }
  __shared__ float att[D_];
  att[d0 + 0] = a0; att[d0 + 1] = a1; att[d0 + 2] = a2; att[d0 + 3] = a3;
  __syncthreads();
  #pragma unroll
  for (int j = 0; j < 4; ++j) {
    int idx = tid + j * 256; int hh = idx >> 6, e = idx & 63;
    float acc = 0.f;
    for (int d = 0; d < DH_; ++d)
      acc += att[(hh << 6) + d] * Wv[((size_t)(hh << 6) + d) * DH_ + e];
    tb[(size_t)n * D_ + idx] = acc;
  }
}

// ---------------------------------------------------------------- split-K GEMM partials
__global__ __launch_bounds__(256) void gemm_part(const float* __restrict__ A1,
                                                 const float* __restrict__ B1,
                                                 const float* __restrict__ A2,
                                                 const float* __restrict__ B2,
                                                 float* __restrict__ Cpart) {
  int col  = blockIdx.x * 32 + (threadIdx.x & 31);
  int row0 = (threadIdx.x >> 5) * 16;
  int k0   = blockIdx.y * (D_ / KS_);
  float acc[16];
  #pragma unroll
  for (int r = 0; r < 16; ++r) acc[r] = 0.f;
  for (int k = k0; k < k0 + (D_ / KS_); k += 4) {
    float b0 = B1[(size_t)(k + 0) * D_ + col];
    float b1 = B1[(size_t)(k + 1) * D_ + col];
    float b2 = B1[(size_t)(k + 2) * D_ + col];
    float b3 = B1[(size_t)(k + 3) * D_ + col];
    #pragma unroll
    for (int r = 0; r < 16; ++r) {
      float4 a = *(const float4*)&A1[(size_t)(row0 + r) * D_ + k];
      acc[r] += a.x * b0 + a.y * b1 + a.z * b2 + a.w * b3;
    }
  }
  if (A2 != nullptr) {
    for (int k = k0; k < k0 + (D_ / KS_); k += 4) {
      float b0 = B2[(size_t)(k + 0) * D_ + col];
      float b1 = B2[(size_t)(k + 1) * D_ + col];
      float b2 = B2[(size_t)(k + 2) * D_ + col];
      float b3 = B2[(size_t)(k + 3) * D_ + col];
      #pragma unroll
      for (int r = 0; r < 16; ++r) {
        float4 a = *(const float4*)&A2[(size_t)(row0 + r) * D_ + k];
        acc[r] += a.x * b0 + a.y * b1 + a.z * b2 + a.w * b3;
      }
    }
  }
  #pragma unroll
  for (int r = 0; r < 16; ++r)
    Cpart[(size_t)blockIdx.y * (N_ * D_) + (size_t)(row0 + r) * D_ + col] = acc[r];
}

// ---------------------------------------------------------------- reduce partials + epilogue
// mode 0: relu(v+bias)   1: v+bias   2: sigmoid(v)*x   3: sigmoid(v-bias)
// mode 4: (1-z)*x + z*tanh(v)
__global__ __launch_bounds__(256) void gemm_combine(const float* __restrict__ Cp,
                                                    const float* __restrict__ bias,
                                                    const float* __restrict__ xb,
                                                    const float* __restrict__ zbuf,
                                                    float* __restrict__ out,
                                                    float* __restrict__ outp,
                                                    int slot, int mode) {
  int idx = blockIdx.x * 256 + threadIdx.x;
  int col = idx & (D_ - 1), row = idx >> 10;
  float v = 0.f;
  #pragma unroll
  for (int s = 0; s < KS_; ++s) v += Cp[(size_t)s * (N_ * D_) + idx];
  switch (mode) {
    case 0: v = fmaxf(v + bias[col], 0.f); break;
    case 1: v = v + bias[col]; break;
    case 2: v = (1.f / (1.f + expf(-v))) * xb[idx]; break;
    case 3: v = 1.f / (1.f + expf(-(v - bias[col]))); break;
    case 4: { float z = zbuf[idx], x = xb[idx]; v = (1.f - z) * x + z * tanhf(v); } break;
  }
  out[idx] = v;
  if (outp != nullptr) {
    size_t bi = (slot >= 0) ? (((size_t)row * NB_ + slot) * D_ + col) : (size_t)idx;
    outp[bi] = v;
  }
}

// ----------------------------------------------------------------
extern "C" void kernel_launch(void* const* d_in, const int* in_sizes, int n_in,
                              void* d_out, int out_size, void* d_ws, size_t ws_size,
                              hipStream_t stream) {
  const float* x    = (const float*)d_in[0];
  const float* mem  = (const float*)d_in[1];
  const int*   mask = (const int*)d_in[2];
  const int*   midx = (const int*)d_in[3];
  const float* We   = (const float*)d_in[5];
  const float* be   = (const float*)d_in[6];
  const float* Wq   = (const float*)d_in[7];
  const float* Wk   = (const float*)d_in[8];
  const float* Wv   = (const float*)d_in[9];
  const float* Wo   = (const float*)d_in[10];
  const float* bo   = (const float*)d_in[11];
  const float* Wfc  = (const float*)d_in[12];
  const float* bfc  = (const float*)d_in[13];
  const float* ln1g = (const float*)d_in[14];
  const float* ln1b = (const float*)d_in[15];
  const float* ln2g = (const float*)d_in[16];
  const float* ln2b = (const float*)d_in[17];
  const float* lnkg = (const float*)d_in[18];
  const float* lnkb = (const float*)d_in[19];
  const float* g1w[7]; for (int j = 0; j < 7; ++j) g1w[j] = (const float*)d_in[20 + j];
  const float* g2w[7]; for (int j = 0; j < 7; ++j) g2w[j] = (const float*)d_in[27 + j];
  float* out = (float*)d_out;          // OUTPUT IS FLOAT32 (reference dtype)
  float* out_li = out + (size_t)N_ * D_;   // layer_inputs region (N, NB, D)

  float* ws   = (float*)d_ws;
  float* pos  = ws; ws += (size_t)T_ * D_;          // 524288
  float* hcur = ws; ws += N_ * D_;
  float* qln  = ws; ws += N_ * D_;
  float* qkb  = ws; ws += N_ * D_;
  float* tb   = ws; ws += N_ * D_;
  float* ao   = ws; ws += N_ * D_;
  float* rq   = ws; ws += N_ * D_;
  float* zb   = ws; ws += N_ * D_;
  float* h1   = ws; ws += N_ * D_;
  float* hl   = ws; ws += N_ * D_;
  float* fwd  = ws; ws += N_ * D_;
  float* E    = ws; ws += (size_t)N_ * H_ * L_;     // 1048576
  float* un   = ws; ws += (size_t)KS_ * N_ * D_;    // gpart == pav (never co-live)
  float* gpart = un;
  float* pav   = un;

  const dim3 gp_grid(32, KS_);
  const dim3 at_grid(NCV_ / 4, N_);

  pos_kernel<<<T_, 512, 0, stream>>>(pos);

  // embed: h0 = relu(x@We + be); layer_inputs[0] = h0
  gemm_part<<<gp_grid, 256, 0, stream>>>(x, We, nullptr, nullptr, gpart);
  gemm_combine<<<512, 256, 0, stream>>>(gpart, be, nullptr, nullptr, hcur,
                                        out_li, 0, 0);

  for (int i = 0; i < NB_; ++i) {
    size_t oD  = (size_t)i * D_;
    size_t oDD = (size_t)i * D_ * D_;
    size_t oH  = (size_t)i * H_ * DH_ * DH_;

    ln_kernel<<<N_, 256, 0, stream>>>(hcur, ln1g + oD, ln1b + oD, qln);
    qk_prep<<<N_, 256, 0, stream>>>(qln, Wq + oH, Wk + oH, qkb);
    attn_energy<<<at_grid, 256, 0, stream>>>(mem, pos, mask, midx, qkb,
                                             lnkg + oD, lnkb + oD, i, E);
    attn_soft<<<N_ * H_, 256, 0, stream>>>(E);
    attn_apply<<<at_grid, 256, 0, stream>>>(mem, pos, midx, E,
                                            lnkg + oD, lnkb + oD, i, pav);
    attn_fin2<<<N_, 256, 0, stream>>>(pav, Wv + oH, tb);

    gemm_part<<<gp_grid, 256, 0, stream>>>(tb, Wo + oDD, nullptr, nullptr, gpart);
    gemm_combine<<<512, 256, 0, stream>>>(gpart, bo + oD, nullptr, nullptr, ao, nullptr, 0, 1);

    // GRU1: x=q(hcur), y=ao
    gemm_part<<<gp_grid, 256, 0, stream>>>(ao, g1w[0] + oDD, hcur, g1w[1] + oDD, gpart);
    gemm_combine<<<512, 256, 0, stream>>>(gpart, nullptr, hcur, nullptr, rq, nullptr, 0, 2);
    gemm_part<<<gp_grid, 256, 0, stream>>>(ao, g1w[2] + oDD, hcur, g1w[3] + oDD, gpart);
    gemm_combine<<<512, 256, 0, stream>>>(gpart, g1w[6] + oD, nullptr, nullptr, zb, nullptr, 0, 3);
    gemm_part<<<gp_grid, 256, 0, stream>>>(ao, g1w[4] + oDD, rq, g1w[5] + oDD, gpart);
    gemm_combine<<<512, 256, 0, stream>>>(gpart, nullptr, hcur, zb, h1, nullptr, 0, 4);

    ln_kernel<<<N_, 256, 0, stream>>>(h1, ln2g + oD, ln2b + oD, hl);
    gemm_part<<<gp_grid, 256, 0, stream>>>(hl, Wfc + oDD, nullptr, nullptr, gpart);
    gemm_combine<<<512, 256, 0, stream>>>(gpart, bfc + oD, nullptr, nullptr, fwd, nullptr, 0, 0);

    // GRU2: x=h1, y=fwd
    gemm_part<<<gp_grid, 256, 0, stream>>>(fwd, g2w[0] + oDD, h1, g2w[1] + oDD, gpart);
    gemm_combine<<<512, 256, 0, stream>>>(gpart, nullptr, h1, nullptr, rq, nullptr, 0, 2);
    gemm_part<<<gp_grid, 256, 0, stream>>>(fwd, g2w[2] + oDD, h1, g2w[3] + oDD, gpart);
    gemm_combine<<<512, 256, 0, stream>>>(gpart, g2w[6] + oD, nullptr, nullptr, zb, nullptr, 0, 3);
    gemm_part<<<gp_grid, 256, 0, stream>>>(fwd, g2w[4] + oDD, rq, g2w[5] + oDD, gpart);
    float* outp = (i < NB_ - 1) ? out_li : out;
    int slot = (i < NB_ - 1) ? (i + 1) : -1;
    gemm_combine<<<512, 256, 0, stream>>>(gpart, nullptr, h1, zb, hcur, outp, slot, 4);
  }
}

// Round 4
// 1882.617 us; speedup vs baseline: 1.3246x; 1.3246x over previous
//
#include <hip/hip_runtime.h>
#include <hip/hip_bf16.h>

#define N_   128
#define L_   512
#define NB_  4
#define D_   1024
#define H_   16
#define DH_  64
#define IN_  1024
#define T_   512

#define KS_  8       // GEMM K-splits (Kc = 128)
#define NCV_ 32      // attention chunks per sample (16 rows each)

// ---------------------------------------------------------------- pos table
__global__ __launch_bounds__(512) void pos_kernel(float* __restrict__ pos) {
  int t = blockIdx.x;          // 0..511
  int j = threadIdx.x;         // 0..511
  float seq = (float)(T_ - 1 - t);
  float ex  = (float)(2 * j) * (1.0f / (float)D_);
  float inv = expf(-ex * 9.210340371976184f);   // 10000^(-2j/D)
  float si  = seq * inv;
  pos[(size_t)t * D_ + j]        = sinf(si);
  pos[(size_t)t * D_ + 512 + j]  = cosf(si);
}

// ---------------------------------------------------------------- split-K GEMM partials
// NC=1024: C = A1@B1a [+ A2@B2a]
// NC=2048: C[:, :1024] = A1@B1a + A2@B2a ; C[:, 1024:] = A1@B1b + A2@B2b
template<int NC>
__global__ __launch_bounds__(256) void gemm_part_t(const float* __restrict__ A1,
                                                   const float* __restrict__ B1a,
                                                   const float* __restrict__ B1b,
                                                   const float* __restrict__ A2,
                                                   const float* __restrict__ B2a,
                                                   const float* __restrict__ B2b,
                                                   float* __restrict__ Cpart) {
  int colg = blockIdx.x * 32 + (threadIdx.x & 31);
  int row0 = (threadIdx.x >> 5) * 16;
  int k0   = blockIdx.y * (D_ / KS_);
  const float* B1 = B1a;
  const float* B2 = B2a;
  int col = colg;
  if (NC == 2048 && colg >= 1024) { B1 = B1b; B2 = B2b; col = colg - 1024; }
  float acc[16];
  #pragma unroll
  for (int r = 0; r < 16; ++r) acc[r] = 0.f;
  for (int k = k0; k < k0 + (D_ / KS_); k += 4) {
    float b0 = B1[(size_t)(k + 0) * D_ + col];
    float b1 = B1[(size_t)(k + 1) * D_ + col];
    float b2 = B1[(size_t)(k + 2) * D_ + col];
    float b3 = B1[(size_t)(k + 3) * D_ + col];
    #pragma unroll
    for (int r = 0; r < 16; ++r) {
      float4 a = *(const float4*)&A1[(size_t)(row0 + r) * D_ + k];
      acc[r] += a.x * b0 + a.y * b1 + a.z * b2 + a.w * b3;
    }
  }
  if (A2 != nullptr) {
    for (int k = k0; k < k0 + (D_ / KS_); k += 4) {
      float b0 = B2[(size_t)(k + 0) * D_ + col];
      float b1 = B2[(size_t)(k + 1) * D_ + col];
      float b2 = B2[(size_t)(k + 2) * D_ + col];
      float b3 = B2[(size_t)(k + 3) * D_ + col];
      #pragma unroll
      for (int r = 0; r < 16; ++r) {
        float4 a = *(const float4*)&A2[(size_t)(row0 + r) * D_ + k];
        acc[r] += a.x * b0 + a.y * b1 + a.z * b2 + a.w * b3;
      }
    }
  }
  #pragma unroll
  for (int r = 0; r < 16; ++r)
    Cpart[(size_t)blockIdx.y * (N_ * NC) + (size_t)(row0 + r) * NC + colg] = acc[r];
}

// ---------------------------------------------------------------- LN + qk fold (device helper)
// block has the full row `val[4]` at cols tid*4..+3; computes LN with g/b, then
// qk[n] = 0.03125 * Wk[h] @ (Wq[h]^T applied... ) identical to prior qk_prep.
__device__ __forceinline__ void ln_qk_epilogue(int n, const float* v4, int tid,
                                               const float* __restrict__ lg,
                                               const float* __restrict__ lb,
                                               const float* __restrict__ Wq,
                                               const float* __restrict__ Wk,
                                               float* __restrict__ qkb,
                                               float* qln, float* Qp /*LDS 1024 each*/) {
  int c = tid * 4;
  float s = v4[0] + v4[1] + v4[2] + v4[3];
  float q = v4[0]*v4[0] + v4[1]*v4[1] + v4[2]*v4[2] + v4[3]*v4[3];
  __shared__ float sa[4], sb[4];
  #pragma unroll
  for (int o = 32; o; o >>= 1) { s += __shfl_xor(s, o, 64); q += __shfl_xor(q, o, 64); }
  if ((tid & 63) == 0) { sa[tid >> 6] = s; sb[tid >> 6] = q; }
  __syncthreads();
  s = sa[0] + sa[1] + sa[2] + sa[3];
  q = sb[0] + sb[1] + sb[2] + sb[3];
  float mean = s * (1.f / D_);
  float var  = q * (1.f / D_) - mean * mean;
  float rstd = rsqrtf(var + 1e-5f);
  #pragma unroll
  for (int j = 0; j < 4; ++j)
    qln[c + j] = (v4[j] - mean) * rstd * lg[c + j] + lb[c + j];
  __syncthreads();
  #pragma unroll
  for (int j = 0; j < 4; ++j) {
    int idx = tid + j * 256; int h = idx >> 6, e = idx & 63;
    float acc = 0.f;
    for (int d = 0; d < DH_; ++d)
      acc += qln[(h << 6) + d] * Wq[((size_t)(h << 6) + d) * DH_ + e];
    Qp[idx] = acc;
  }
  __syncthreads();
  #pragma unroll
  for (int j = 0; j < 4; ++j) {
    int idx = tid + j * 256; int h = idx >> 6, d = idx & 63;
    float acc = 0.f;
    for (int e = 0; e < DH_; ++e)
      acc += Wk[((size_t)(h << 6) + d) * DH_ + e] * Qp[(h << 6) + e];
    qkb[(size_t)n * D_ + idx] = acc * 0.03125f;   // 1/sqrt(1024)
  }
}

// ---------------------------------------------------------------- embed combine: relu(v+be) -> hcur, out_li[0], LN1+qk
__global__ __launch_bounds__(256) void comb_embed_lnqk(const float* __restrict__ Cp,
                                                       const float* __restrict__ bias,
                                                       const float* __restrict__ lg,
                                                       const float* __restrict__ lb,
                                                       const float* __restrict__ Wq,
                                                       const float* __restrict__ Wk,
                                                       float* __restrict__ hcur,
                                                       float* __restrict__ out_li,
                                                       float* __restrict__ qkb) {
  int n = blockIdx.x, tid = threadIdx.x, c = tid * 4;
  __shared__ float qln[D_], Qp[D_];
  float v[4];
  #pragma unroll
  for (int j = 0; j < 4; ++j) {
    float acc = 0.f;
    #pragma unroll
    for (int s = 0; s < KS_; ++s) acc += Cp[(size_t)s * (N_ * D_) + (size_t)n * D_ + c + j];
    v[j] = fmaxf(acc + bias[c + j], 0.f);
    hcur[(size_t)n * D_ + c + j] = v[j];
    out_li[((size_t)n * NB_ + 0) * D_ + c + j] = v[j];
  }
  ln_qk_epilogue(n, v, tid, lg, lb, Wq, Wk, qkb, qln, Qp);
}

// ---------------------------------------------------------------- streaming attention (flash-decode, online softmax)
__global__ __launch_bounds__(256) void attn_stream(
    const float* __restrict__ mem, const float* __restrict__ pos,
    const int* __restrict__ mask, const int* __restrict__ midx,
    const float* __restrict__ qkv, const float* __restrict__ lng,
    const float* __restrict__ lnb, int blk,
    float* __restrict__ pav, float* __restrict__ pm, float* __restrict__ ps)
{
  const int n    = blockIdx.y;
  const int w    = threadIdx.x >> 6;
  const int lane = threadIdx.x & 63;
  const int vc   = blockIdx.x * 4 + w;       // 0..31
  const int l0   = vc * (L_ / NCV_);         // 16 rows per wave
  const int d0   = lane * 16;

  float g[16], bv[16], qv[16];
  #pragma unroll
  for (int j = 0; j < 4; ++j) {
    float4 t0 = *(const float4*)&lng[d0 + 4 * j];
    g[4*j+0] = t0.x; g[4*j+1] = t0.y; g[4*j+2] = t0.z; g[4*j+3] = t0.w;
    float4 t1 = *(const float4*)&lnb[d0 + 4 * j];
    bv[4*j+0] = t1.x; bv[4*j+1] = t1.y; bv[4*j+2] = t1.z; bv[4*j+3] = t1.w;
    float4 t2 = *(const float4*)&qkv[(size_t)n * D_ + d0 + 4 * j];
    qv[4*j+0] = t2.x; qv[4*j+1] = t2.y; qv[4*j+2] = t2.z; qv[4*j+3] = t2.w;
  }
  float m_run = -INFINITY, s_run = 0.f;
  float av[16];
  #pragma unroll
  for (int j = 0; j < 16; ++j) av[j] = 0.f;

  for (int l = l0; l < l0 + (L_ / NCV_); ++l) {
    if (mask[(size_t)n * L_ + l] == 0) continue;   // wave-uniform
    const float* xr = &mem[(((size_t)n * L_ + l) * NB_ + blk) * D_ + d0];
    const int tt = midx[(size_t)n * L_ + l];
    const float* pr = &pos[(size_t)tt * D_ + d0];
    float xv[16];
    #pragma unroll
    for (int j = 0; j < 4; ++j) {
      float4 a = *(const float4*)&xr[4 * j];
      float4 p = *(const float4*)&pr[4 * j];
      xv[4*j+0] = a.x + p.x; xv[4*j+1] = a.y + p.y;
      xv[4*j+2] = a.z + p.z; xv[4*j+3] = a.w + p.w;
    }
    float s1 = 0.f, s2 = 0.f;
    #pragma unroll
    for (int j = 0; j < 16; ++j) { s1 += xv[j]; s2 += xv[j] * xv[j]; }
    #pragma unroll
    for (int o = 32; o; o >>= 1) { s1 += __shfl_xor(s1, o, 64); s2 += __shfl_xor(s2, o, 64); }
    float mean = s1 * (1.f / D_);
    float var  = s2 * (1.f / D_) - mean * mean;
    float rstd = rsqrtf(var + 1e-5f);
    float e = 0.f;
    float y[16];
    #pragma unroll
    for (int j = 0; j < 16; ++j) {
      y[j] = (xv[j] - mean) * rstd * g[j] + bv[j];
      e += y[j] * qv[j];
    }
    e += __shfl_xor(e, 1, 64);
    e += __shfl_xor(e, 2, 64);     // 4-lane head group all hold full e
    float mn = fmaxf(m_run, e);
    float al = __expf(m_run - mn);
    float pw = __expf(e - mn);
    s_run = s_run * al + pw;
    #pragma unroll
    for (int j = 0; j < 16; ++j) av[j] = av[j] * al + pw * y[j];
    m_run = mn;
  }
  size_t base = ((size_t)n * NCV_ + vc) * D_ + d0;
  #pragma unroll
  for (int j = 0; j < 16; ++j) pav[base + j] = av[j];
  if ((lane & 3) == 0) {
    size_t mb = ((size_t)n * NCV_ + vc) * H_ + (lane >> 2);
    pm[mb] = m_run;
    ps[mb] = s_run;
  }
}

// ---------------------------------------------------------------- merge chunks + V-projection -> tb
__global__ __launch_bounds__(256) void attn_fin(const float* __restrict__ pav,
                                                const float* __restrict__ pm,
                                                const float* __restrict__ ps,
                                                const float* __restrict__ Wv,
                                                float* __restrict__ tb) {
  int n = blockIdx.x, tid = threadIdx.x;
  int d0 = tid * 4; int h = tid >> 4;
  float M = -INFINITY;
  for (int c = 0; c < NCV_; ++c) M = fmaxf(M, pm[((size_t)n * NCV_ + c) * H_ + h]);
  float S = 0.f, a0 = 0.f, a1 = 0.f, a2 = 0.f, a3 = 0.f;
  if (M > -INFINITY) {
    for (int c = 0; c < NCV_; ++c) {
      float mc = pm[((size_t)n * NCV_ + c) * H_ + h];
      if (mc == -INFINITY) continue;
      float wgt = __expf(mc - M);
      S += ps[((size_t)n * NCV_ + c) * H_ + h] * wgt;
      size_t ab = ((size_t)n * NCV_ + c) * D_ + d0;
      a0 += pav[ab + 0] * wgt; a1 += pav[ab + 1] * wgt;
      a2 += pav[ab + 2] * wgt; a3 += pav[ab + 3] * wgt;
    }
  }
  float inv = (S > 0.f) ? 1.f / S : 0.f;
  __shared__ float att[D_];
  att[d0 + 0] = a0 * inv; att[d0 + 1] = a1 * inv;
  att[d0 + 2] = a2 * inv; att[d0 + 3] = a3 * inv;
  __syncthreads();
  #pragma unroll
  for (int j = 0; j < 4; ++j) {
    int idx = tid + j * 256; int hh = idx >> 6, e = idx & 63;
    float acc = 0.f;
    for (int d = 0; d < DH_; ++d)
      acc += att[(hh << 6) + d] * Wv[((size_t)(hh << 6) + d) * DH_ + e];
    tb[(size_t)n * D_ + idx] = acc;
  }
}

// ---------------------------------------------------------------- elementwise combine: mode 0 relu(v+b), 1 v+b
__global__ __launch_bounds__(256) void comb_ew(const float* __restrict__ Cp,
                                               const float* __restrict__ bias,
                                               float* __restrict__ out, int mode) {
  int idx = blockIdx.x * 256 + threadIdx.x;
  int col = idx & (D_ - 1);
  float v = 0.f;
  #pragma unroll
  for (int s = 0; s < KS_; ++s) v += Cp[(size_t)s * (N_ * D_) + idx];
  v += bias[col];
  if (mode == 0) v = fmaxf(v, 0.f);
  out[idx] = v;
}

// ---------------------------------------------------------------- GRU r,z combine from 2048-wide partials
// rq = sigmoid(vr) * x ; zb = sigmoid(vz - bg)
__global__ __launch_bounds__(256) void comb_rz(const float* __restrict__ Cp2,
                                               const float* __restrict__ bg,
                                               const float* __restrict__ xb,
                                               float* __restrict__ rq,
                                               float* __restrict__ zb) {
  int idx = blockIdx.x * 256 + threadIdx.x;      // 0..131071
  int row = idx >> 10, col = idx & (D_ - 1);
  float vr = 0.f, vz = 0.f;
  #pragma unroll
  for (int s = 0; s < KS_; ++s) {
    size_t b = (size_t)s * (N_ * 2048) + (size_t)row * 2048 + col;
    vr += Cp2[b];
    vz += Cp2[b + 1024];
  }
  rq[idx] = (1.f / (1.f + __expf(-vr))) * xb[idx];
  zb[idx] = 1.f / (1.f + __expf(-(vz - bg[col])));
}

// ---------------------------------------------------------------- GRU1 h combine + LN2 -> h1, hl
__global__ __launch_bounds__(256) void comb_h_ln(const float* __restrict__ Cp,
                                                 const float* __restrict__ zb,
                                                 const float* __restrict__ xb,
                                                 const float* __restrict__ lg,
                                                 const float* __restrict__ lb,
                                                 float* __restrict__ h1,
                                                 float* __restrict__ hl) {
  int n = blockIdx.x, tid = threadIdx.x, c = tid * 4;
  float v[4];
  float s = 0.f, q = 0.f;
  #pragma unroll
  for (int j = 0; j < 4; ++j) {
    float acc = 0.f;
    #pragma unroll
    for (int ss = 0; ss < KS_; ++ss) acc += Cp[(size_t)ss * (N_ * D_) + (size_t)n * D_ + c + j];
    float z = zb[(size_t)n * D_ + c + j];
    float x = xb[(size_t)n * D_ + c + j];
    v[j] = (1.f - z) * x + z * tanhf(acc);
    h1[(size_t)n * D_ + c + j] = v[j];
    s += v[j]; q += v[j] * v[j];
  }
  __shared__ float sa[4], sb[4];
  #pragma unroll
  for (int o = 32; o; o >>= 1) { s += __shfl_xor(s, o, 64); q += __shfl_xor(q, o, 64); }
  if ((tid & 63) == 0) { sa[tid >> 6] = s; sb[tid >> 6] = q; }
  __syncthreads();
  s = sa[0] + sa[1] + sa[2] + sa[3];
  q = sb[0] + sb[1] + sb[2] + sb[3];
  float mean = s * (1.f / D_);
  float var  = q * (1.f / D_) - mean * mean;
  float rstd = rsqrtf(var + 1e-5f);
  #pragma unroll
  for (int j = 0; j < 4; ++j)
    hl[(size_t)n * D_ + c + j] = (v[j] - mean) * rstd * lg[c + j] + lb[c + j];
}

// ---------------------------------------------------------------- GRU2 h combine -> hcur, out slot, optional LN1+qk(next)
__global__ __launch_bounds__(256) void comb_h2_lnqk(const float* __restrict__ Cp,
                                                    const float* __restrict__ zb,
                                                    const float* __restrict__ xb,
                                                    const float* __restrict__ lg,
                                                    const float* __restrict__ lb,
                                                    const float* __restrict__ Wq,
                                                    const float* __restrict__ Wk,
                                                    float* __restrict__ hcur,
                                                    float* __restrict__ outp,
                                                    int slot,
                                                    float* __restrict__ qkb) {
  int n = blockIdx.x, tid = threadIdx.x, c = tid * 4;
  __shared__ float qln[D_], Qp[D_];
  float v[4];
  #pragma unroll
  for (int j = 0; j < 4; ++j) {
    float acc = 0.f;
    #pragma unroll
    for (int ss = 0; ss < KS_; ++ss) acc += Cp[(size_t)ss * (N_ * D_) + (size_t)n * D_ + c + j];
    float z = zb[(size_t)n * D_ + c + j];
    float x = xb[(size_t)n * D_ + c + j];
    v[j] = (1.f - z) * x + z * tanhf(acc);
    hcur[(size_t)n * D_ + c + j] = v[j];
    size_t bi = (slot >= 0) ? (((size_t)n * NB_ + slot) * D_ + c + j)
                            : ((size_t)n * D_ + c + j);
    outp[bi] = v[j];
  }
  if (Wq != nullptr)
    ln_qk_epilogue(n, v, tid, lg, lb, Wq, Wk, qkb, qln, Qp);
}

// ----------------------------------------------------------------
extern "C" void kernel_launch(void* const* d_in, const int* in_sizes, int n_in,
                              void* d_out, int out_size, void* d_ws, size_t ws_size,
                              hipStream_t stream) {
  const float* x    = (const float*)d_in[0];
  const float* mem  = (const float*)d_in[1];
  const int*   mask = (const int*)d_in[2];
  const int*   midx = (const int*)d_in[3];
  const float* We   = (const float*)d_in[5];
  const float* be   = (const float*)d_in[6];
  const float* Wq   = (const float*)d_in[7];
  const float* Wk   = (const float*)d_in[8];
  const float* Wv   = (const float*)d_in[9];
  const float* Wo   = (const float*)d_in[10];
  const float* bo   = (const float*)d_in[11];
  const float* Wfc  = (const float*)d_in[12];
  const float* bfc  = (const float*)d_in[13];
  const float* ln1g = (const float*)d_in[14];
  const float* ln1b = (const float*)d_in[15];
  const float* ln2g = (const float*)d_in[16];
  const float* ln2b = (const float*)d_in[17];
  const float* lnkg = (const float*)d_in[18];
  const float* lnkb = (const float*)d_in[19];
  const float* g1w[7]; for (int j = 0; j < 7; ++j) g1w[j] = (const float*)d_in[20 + j];
  const float* g2w[7]; for (int j = 0; j < 7; ++j) g2w[j] = (const float*)d_in[27 + j];
  float* out = (float*)d_out;
  float* out_li = out + (size_t)N_ * D_;   // layer_inputs region (N, NB, D)

  float* ws   = (float*)d_ws;
  float* pos  = ws; ws += (size_t)T_ * D_;
  float* hcur = ws; ws += N_ * D_;
  float* qkb  = ws; ws += N_ * D_;
  float* tb   = ws; ws += N_ * D_;
  float* ao   = ws; ws += N_ * D_;
  float* rq   = ws; ws += N_ * D_;
  float* zb   = ws; ws += N_ * D_;
  float* h1   = ws; ws += N_ * D_;
  float* hl   = ws; ws += N_ * D_;
  float* fwd  = ws; ws += N_ * D_;
  float* gpart = ws; ws += (size_t)KS_ * N_ * 2048;    // wide enough for 2048-col
  float* pav   = ws; ws += (size_t)N_ * NCV_ * D_;     // 16 MB
  float* pm    = ws; ws += (size_t)N_ * NCV_ * H_;
  float* ps    = ws; ws += (size_t)N_ * NCV_ * H_;

  const dim3 gp1(32, KS_);     // 1024-col GEMM
  const dim3 gp2(64, KS_);     // 2048-col GEMM
  const dim3 at_grid(NCV_ / 4, N_);

  pos_kernel<<<T_, 512, 0, stream>>>(pos);

  // embed: h0 = relu(x@We + be); out_li[0]; LN1(layer0)+qk fold
  gemm_part_t<1024><<<gp1, 256, 0, stream>>>(x, We, nullptr, nullptr, nullptr, nullptr, gpart);
  comb_embed_lnqk<<<N_, 256, 0, stream>>>(gpart, be, ln1g, ln1b, Wq, Wk, hcur, out_li, qkb);

  for (int i = 0; i < NB_; ++i) {
    size_t oD  = (size_t)i * D_;
    size_t oDD = (size_t)i * D_ * D_;
    size_t oH  = (size_t)i * H_ * DH_ * DH_;

    attn_stream<<<at_grid, 256, 0, stream>>>(mem, pos, mask, midx, qkb,
                                             lnkg + oD, lnkb + oD, i, pav, pm, ps);
    attn_fin<<<N_, 256, 0, stream>>>(pav, pm, ps, Wv + oH, tb);

    gemm_part_t<1024><<<gp1, 256, 0, stream>>>(tb, Wo + oDD, nullptr, nullptr, nullptr, nullptr, gpart);
    comb_ew<<<512, 256, 0, stream>>>(gpart, bo + oD, ao, 1);

    // GRU1: x=hcur, y=ao.  r|z wide GEMM then h GEMM
    gemm_part_t<2048><<<gp2, 256, 0, stream>>>(ao, g1w[0] + oDD, g1w[2] + oDD,
                                               hcur, g1w[1] + oDD, g1w[3] + oDD, gpart);
    comb_rz<<<512, 256, 0, stream>>>(gpart, g1w[6] + oD, hcur, rq, zb);
    gemm_part_t<1024><<<gp1, 256, 0, stream>>>(ao, g1w[4] + oDD, nullptr, rq, g1w[5] + oDD, nullptr, gpart);
    comb_h_ln<<<N_, 256, 0, stream>>>(gpart, zb, hcur, ln2g + oD, ln2b + oD, h1, hl);

    gemm_part_t<1024><<<gp1, 256, 0, stream>>>(hl, Wfc + oDD, nullptr, nullptr, nullptr, nullptr, gpart);
    comb_ew<<<512, 256, 0, stream>>>(gpart, bfc + oD, fwd, 0);

    // GRU2: x=h1, y=fwd
    gemm_part_t<2048><<<gp2, 256, 0, stream>>>(fwd, g2w[0] + oDD, g2w[2] + oDD,
                                               h1, g2w[1] + oDD, g2w[3] + oDD, gpart);
    comb_rz<<<512, 256, 0, stream>>>(gpart, g2w[6] + oD, h1, rq, zb);
    gemm_part_t<1024><<<gp1, 256, 0, stream>>>(fwd, g2w[4] + oDD, nullptr, rq, g2w[5] + oDD, nullptr, gpart);

    bool last = (i == NB_ - 1);
    float* outp = last ? out : out_li;
    int slot = last ? -1 : (i + 1);
    const float* nWq = last ? nullptr : (Wq + oH + H_ * DH_ * DH_);
    const float* nWk = last ? nullptr : (Wk + oH + H_ * DH_ * DH_);
    const float* nlg = last ? nullptr : (ln1g + oD + D_);
    const float* nlb = last ? nullptr : (ln1b + oD + D_);
    comb_h2_lnqk<<<N_, 256, 0, stream>>>(gpart, zb, h1, nlg, nlb, nWq, nWk,
                                         hcur, outp, slot, qkb);
  }
}